// Round 2
// baseline (620.856 us; speedup 1.0000x reference)
//
#include <hip/hip_runtime.h>

#define N_FEAT 128
#define F1 16
#define F2 2

// ---------------- degree histogram over dst ----------------
__global__ void deg_kernel(const int* __restrict__ col, int E, int* __restrict__ deg) {
    int i = blockIdx.x * blockDim.x + threadIdx.x;
    if (i < E) atomicAdd(&deg[col[i]], 1);
}

// ---------------- scan step 1: per-block sums ----------------
__global__ void scan1_kernel(const int* __restrict__ deg, int* __restrict__ bs, int N) {
    __shared__ int s[256];
    int t = threadIdx.x, i = blockIdx.x * 256 + t;
    s[t] = (i < N) ? deg[i] : 0;
    __syncthreads();
    for (int off = 128; off > 0; off >>= 1) {
        if (t < off) s[t] += s[t + off];
        __syncthreads();
    }
    if (t == 0) bs[blockIdx.x] = s[0];
}

// ---------------- scan step 2: exclusive scan of block sums (nb <= 1024) -----
__global__ void scan2_kernel(int* __restrict__ bs, int nb) {
    __shared__ int s[1024];
    int t = threadIdx.x;
    int orig = (t < nb) ? bs[t] : 0;
    s[t] = orig;
    __syncthreads();
    for (int off = 1; off < 1024; off <<= 1) {
        int v = (t >= off) ? s[t - off] : 0;
        __syncthreads();
        s[t] += v;
        __syncthreads();
    }
    if (t < nb) bs[t] = s[t] - orig;  // exclusive
}

// ---------------- scan step 3: per-element exclusive scan + dinv -------------
__global__ void scan3_kernel(const int* __restrict__ deg, const int* __restrict__ bs,
                             int* __restrict__ cursor, float* __restrict__ dinv, int N) {
    __shared__ int s[256];
    int t = threadIdx.x, i = blockIdx.x * 256 + t;
    int v = (i < N) ? deg[i] : 0;
    s[t] = v;
    __syncthreads();
    for (int off = 1; off < 256; off <<= 1) {
        int u = (t >= off) ? s[t - off] : 0;
        __syncthreads();
        s[t] += u;
        __syncthreads();
    }
    if (i < N) {
        cursor[i] = bs[blockIdx.x] + s[t] - v;      // row start
        dinv[i] = rsqrtf((float)(v + 1));           // +1 self loop
    }
}

// ---------------- CSR fill: srcOf sorted by dst; cursor -> row end -----------
__global__ void fill_kernel(const int* __restrict__ rowi, const int* __restrict__ coli,
                            int* __restrict__ cursor, int* __restrict__ srcOf, int E) {
    int e = blockIdx.x * blockDim.x + threadIdx.x;
    if (e >= E) return;
    int c = coli[e];
    int p = atomicAdd(&cursor[c], 1);
    srcOf[p] = rowi[e];
}

// ---------------- layer-1 GEMM: hs[r,f] = dinv[r] * sum_k x[r,k]*W1[k,f] -----
__global__ __launch_bounds__(256) void gemm1_kernel(
    const float* __restrict__ x, const float* __restrict__ W1,
    const float* __restrict__ dinv, float* __restrict__ hs, int N) {
    __shared__ float ws[N_FEAT * F1];
    __shared__ float xs[16][N_FEAT];
    int t = threadIdx.x;
    for (int i = t; i < N_FEAT * F1; i += 256) ws[i] = W1[i];
    int row0 = blockIdx.x * 16;
    for (int i = t; i < 16 * N_FEAT; i += 256) {
        int r = i >> 7, k = i & 127;
        int row = row0 + r;
        xs[r][k] = (row < N) ? x[row * N_FEAT + k] : 0.f;
    }
    __syncthreads();
    int rr = t >> 4, f = t & 15;
    int row = row0 + rr;
    if (row < N) {
        float acc = 0.f;
#pragma unroll
        for (int k = 0; k < N_FEAT; ++k) acc += xs[rr][k] * ws[k * F1 + f];
        hs[row * F1 + f] = acc * dinv[row];
    }
}

// ---------------- gather layer 1: acc[c,:] = sum_{e: dst=c} hs[src(e),:] -----
__global__ __launch_bounds__(256) void gather1_kernel(
    const int* __restrict__ cursorEnd, const int* __restrict__ deg,
    const int* __restrict__ srcOf, const float* __restrict__ hs,
    float* __restrict__ acc, int N) {
    int gid = blockIdx.x * blockDim.x + threadIdx.x;
    int node = gid >> 4, f = gid & 15;
    if (node >= N) return;
    int d = deg[node];
    int base = cursorEnd[node] - d;
    float a = 0.f;
    for (int k = 0; k < d; k += 16) {
        int idx = k + f;
        int src = (idx < d) ? srcOf[base + idx] : 0;   // coalesced 64B
        int lim = min(16, d - k);
        for (int j = 0; j < lim; ++j) {
            int sj = __shfl(src, j, 16);               // broadcast within group
            a += hs[sj * F1 + f];                      // coalesced 64B gather
        }
    }
    acc[node * F1 + f] = a;
}

// ---------------- finalize layer 1 + relu + GEMM2 ----------------------------
__global__ __launch_bounds__(256) void layer2_kernel(
    const float* __restrict__ acc, const float* __restrict__ hs,
    const float* __restrict__ dinv, const float* __restrict__ b1,
    const float* __restrict__ W2, float* __restrict__ hs2, int N) {
    __shared__ float w2s[F1 * F2];
    __shared__ float b1s[F1];
    int t = threadIdx.x;
    if (t < F1 * F2) w2s[t] = W2[t];
    if (t < F1) b1s[t] = b1[t];
    __syncthreads();
    int i = blockIdx.x * blockDim.x + t;
    if (i >= N) return;
    float di = dinv[i];
    const float4* a4 = (const float4*)(acc + (size_t)i * F1);
    const float4* s4 = (const float4*)(hs + (size_t)i * F1);
    float h0 = 0.f, h1 = 0.f;
#pragma unroll
    for (int q = 0; q < 4; ++q) {
        float4 a = a4[q], s = s4[q];
        float v[4] = {a.x + s.x, a.y + s.y, a.z + s.z, a.w + s.w};
#pragma unroll
        for (int u = 0; u < 4; ++u) {
            int f = q * 4 + u;
            float o = fmaxf(di * v[u] + b1s[f], 0.f);
            h0 += o * w2s[f * F2 + 0];
            h1 += o * w2s[f * F2 + 1];
        }
    }
    hs2[(size_t)i * F2 + 0] = h0 * di;
    hs2[(size_t)i * F2 + 1] = h1 * di;
}

// ---------------- gather layer 2 + finalize + bias ---------------------------
__global__ __launch_bounds__(256) void gather2_kernel(
    const int* __restrict__ cursorEnd, const int* __restrict__ deg,
    const int* __restrict__ srcOf, const float* __restrict__ hs2,
    const float* __restrict__ dinv, const float* __restrict__ b2,
    float* __restrict__ out, int N) {
    int gid = blockIdx.x * blockDim.x + threadIdx.x;
    int node = gid >> 4, f = gid & 15;
    if (node >= N) return;
    int d = deg[node];
    int base = cursorEnd[node] - d;
    float a0 = 0.f, a1 = 0.f;
    for (int idx = f; idx < d; idx += 16) {
        int src = srcOf[base + idx];                   // coalesced 64B
        float2 v = ((const float2*)hs2)[src];          // 8B, L2-resident
        a0 += v.x;
        a1 += v.y;
    }
    for (int off = 8; off; off >>= 1) {
        a0 += __shfl_xor(a0, off, 16);
        a1 += __shfl_xor(a1, off, 16);
    }
    if (f == 0) {
        float di = dinv[node];
        float2 s = ((const float2*)hs2)[node];
        float2 o;
        o.x = di * (a0 + s.x) + b2[0];
        o.y = di * (a1 + s.y) + b2[1];
        ((float2*)out)[node] = o;
    }
}

extern "C" void kernel_launch(void* const* d_in, const int* in_sizes, int n_in,
                              void* d_out, int out_size, void* d_ws, size_t ws_size,
                              hipStream_t stream) {
    const float* x  = (const float*)d_in[0];
    const int*   ei = (const int*)d_in[1];
    const float* W1 = (const float*)d_in[2];
    const float* b1 = (const float*)d_in[3];
    const float* W2 = (const float*)d_in[4];
    const float* b2 = (const float*)d_in[5];
    int N = in_sizes[0] / N_FEAT;
    int E = in_sizes[1] / 2;
    const int* rowi = ei;        // src
    const int* coli = ei + E;    // dst
    float* out = (float*)d_out;

    // workspace layout, regions padded to 1024-element alignment
    size_t NP = ((size_t)N + 1023) & ~(size_t)1023;
    size_t EP = ((size_t)E + 1023) & ~(size_t)1023;
    char* w = (char*)d_ws;
    int*   deg    = (int*)w;                    w += NP * 4;
    int*   cursor = (int*)w;                    w += NP * 4;
    int*   bs     = (int*)w;                    w += 1024 * 4;
    float* dinv   = (float*)w;                  w += NP * 4;
    int*   srcOf  = (int*)w;                    w += EP * 4;
    float* hs     = (float*)w;                  w += NP * F1 * 4;
    float* acc    = (float*)w;                  w += NP * F1 * 4;
    float* hs2    = (float*)w;                  w += NP * F2 * 4;

    int nbN = (N + 255) / 256;    // 391
    int nbE = (E + 255) / 256;    // 12500

    hipMemsetAsync(deg, 0, (size_t)N * sizeof(int), stream);

    deg_kernel<<<nbE, 256, 0, stream>>>(coli, E, deg);
    scan1_kernel<<<nbN, 256, 0, stream>>>(deg, bs, N);
    scan2_kernel<<<1, 1024, 0, stream>>>(bs, nbN);
    scan3_kernel<<<nbN, 256, 0, stream>>>(deg, bs, cursor, dinv, N);
    fill_kernel<<<nbE, 256, 0, stream>>>(rowi, coli, cursor, srcOf, E);  // cursor -> row end

    gemm1_kernel<<<(N + 15) / 16, 256, 0, stream>>>(x, W1, dinv, hs, N);
    gather1_kernel<<<(int)((16LL * N + 255) / 256), 256, 0, stream>>>(cursor, deg, srcOf, hs, acc, N);
    layer2_kernel<<<nbN, 256, 0, stream>>>(acc, hs, dinv, b1, W2, hs2, N);
    gather2_kernel<<<(int)((16LL * N + 255) / 256), 256, 0, stream>>>(cursor, deg, srcOf, hs2, dinv, b2, out, N);
}